// Round 7
// baseline (281.556 us; speedup 1.0000x reference)
//
#include <hip/hip_runtime.h>
#include <hip/hip_bf16.h>

typedef _Float16 half4_t  __attribute__((ext_vector_type(4)));
typedef _Float16 half8_t  __attribute__((ext_vector_type(8)));
typedef float    float4_t __attribute__((ext_vector_type(4)));

#define MFMA16x32(a, b, c) __builtin_amdgcn_mfma_f32_16x16x32_f16(a, b, c, 0, 0, 0)

// ===========================================================================
// FUSED single-kernel pipeline: [A] W fp32->fp16 frag-layout cvt, [B] QKV
// projection (proj3 structure, R6-verified), [C] flash cross-attention
// (R0 structure, best measured 87.4us). Rationale (R4/R6 accounting): each
// kernel boundary cost ~25-40us of dispatch gap + L2 flush; 3-kernel rounds
// carried 60-80us of inter-dispatch overhead. One kernel + 2 grid barriers
// removes it.
//
// Grid 256 blocks x 512 thr = 1 block/CU on 256 CUs -> all blocks resident
// (LDS 47KB, VGPR fits 2 waves/SIMD), so a device-scope atomic grid barrier
// is safe. Barrier: monotonic arrive counter in d_out scratch (reset by a
// hipMemsetAsync node each graph launch; d_out is fully overwritten by
// phase C's epilogue AFTER the last barrier use). Spin uses device-scope
// atomicAdd (cross-XCD coherent); __threadfence release/acquire around it.
// ===========================================================================
__global__ __launch_bounds__(512, 1)
void fused_kernel(const float* __restrict__ tokens, const float* __restrict__ context,
                  const float* __restrict__ Wq, const float* __restrict__ Wk,
                  const float* __restrict__ Wv,
                  _Float16* __restrict__ Qws, _Float16* __restrict__ Kws,
                  _Float16* __restrict__ Vws,
                  unsigned* __restrict__ syncp, _Float16* __restrict__ W16,
                  float* __restrict__ out) {
  __shared__ alignas(16) _Float16 smem[23040];  // phase B: Vb 320x72 (46KB); phase C: kbuf|pbuf (16KB) aliased
  __shared__ float larr[2][4][16];
  __shared__ float linv[64];

  const int tid = threadIdx.x, w = tid >> 6, lane = tid & 63;
  const int G = lane >> 4, l15 = lane & 15;
  const int bx = blockIdx.x;

  // ---- device-scope grid barrier (monotonic counter, targets 256/512) ----
  auto gbar = [&](unsigned target) {
    __syncthreads();
    if (tid == 0) {
      __threadfence();                       // release this block's writes
      atomicAdd(syncp, 1u);
      while (atomicAdd(syncp, 0u) < target) __builtin_amdgcn_s_sleep(2);
      __threadfence();                       // acquire other blocks' writes
    }
    __syncthreads();
  };

  // ======================= phase A: W cvt to frag layout ====================
  // WQf [0,20480): g=((kc*4+nt)*2+c)*64+ln -> Wq[nt*16+(ln&15)][kc*64+c*32+8*(ln>>4)..+8]
  // WKVf [20480,+294912): g=((kc*24+nt)*2+c)*64+ln; nt<4 Wk row, nt>=4 Wv row-64.
  {
    const int gtid = bx * 512 + tid;
    if (gtid < 39424) {
      const float* src;
      _Float16* dst;
      if (gtid < 2560) {
        int g = gtid;
        int ln = g & 63, c = (g >> 6) & 1, rest = g >> 7;
        int nt = rest & 3, kc = rest >> 2;
        int n = nt * 16 + (ln & 15), k0 = kc * 64 + c * 32 + 8 * (ln >> 4);
        src = Wq + n * 320 + k0;
        dst = W16 + (size_t)g * 8;
      } else {
        int g = gtid - 2560;
        int ln = g & 63, c = (g >> 6) & 1, rest = g >> 7;
        int nt = rest % 24, kc = rest / 24;
        int n = nt * 16 + (ln & 15), k0 = kc * 64 + c * 32 + 8 * (ln >> 4);
        src = (nt < 4) ? (Wk + n * 768 + k0) : (Wv + (n - 64) * 768 + k0);
        dst = W16 + 20480 + (size_t)g * 8;
      }
      float4_t a = *(const float4_t*)(src);
      float4_t b2 = *(const float4_t*)(src + 4);
      half8_t h = {(_Float16)a[0], (_Float16)a[1], (_Float16)a[2], (_Float16)a[3],
                   (_Float16)b2[0], (_Float16)b2[1], (_Float16)b2[2], (_Float16)b2[3]};
      *(half8_t*)dst = h;
    }
  }
  gbar(256);

  // ======================= phase B: QKV projection ==========================
  // Per block: waves 0-3 = ctx tile bx (fused K+V, 16 rows/wave, 24 n-tiles);
  // waves 4-7 = Q tile bx (16 rows/wave, 4 n-tiles). Identical per-wave work
  // to R6's proj3 (512 blocks x 4 waves == 256 blocks x 8 waves).
  {
    _Float16* Vb = smem;
    const _Float16* WQf = W16;
    const _Float16* WKVf = W16 + 20480;
    const int m0 = bx * 64;

    if (w < 4) {
      // ---------------- fused K+V over context m-tile ----------------------
      const float* arow = context + (size_t)(m0 + w * 16 + l15) * 768;
      float4_t ar[4];
      auto ldA = [&](int kc) {
        ar[0] = *(const float4_t*)(arow + kc * 64 + 8 * G);
        ar[1] = *(const float4_t*)(arow + kc * 64 + 8 * G + 4);
        ar[2] = *(const float4_t*)(arow + kc * 64 + 32 + 8 * G);
        ar[3] = *(const float4_t*)(arow + kc * 64 + 36 + 8 * G);
      };
      float4_t acc[24];
#pragma unroll
      for (int nt = 0; nt < 24; ++nt) acc[nt] = {0.f, 0.f, 0.f, 0.f};
      half8_t bf[2][4][2];
      auto ldW = [&](int buf, int kc, int g) {
#pragma unroll
        for (int j = 0; j < 4; ++j)
#pragma unroll
          for (int c = 0; c < 2; ++c)
            bf[buf][j][c] = *(const half8_t*)(WKVf + ((size_t)(((kc * 24 + g * 4 + j) * 2) + c) * 64 + lane) * 8);
      };
      ldA(0);
      ldW(0, 0, 0);
      for (int kc = 0; kc < 12; ++kc) {
        half8_t af0 = {(_Float16)ar[0][0], (_Float16)ar[0][1], (_Float16)ar[0][2], (_Float16)ar[0][3],
                       (_Float16)ar[1][0], (_Float16)ar[1][1], (_Float16)ar[1][2], (_Float16)ar[1][3]};
        half8_t af1 = {(_Float16)ar[2][0], (_Float16)ar[2][1], (_Float16)ar[2][2], (_Float16)ar[2][3],
                       (_Float16)ar[3][0], (_Float16)ar[3][1], (_Float16)ar[3][2], (_Float16)ar[3][3]};
        if (kc < 11) ldA(kc + 1);
#pragma unroll
        for (int g = 0; g < 6; ++g) {
          if (g < 5) ldW((g + 1) & 1, kc, g + 1);
          else if (kc < 11) ldW(0, kc + 1, 0);
#pragma unroll
          for (int j = 0; j < 4; ++j) acc[g * 4 + j] = MFMA16x32(af0, bf[g & 1][j][0], acc[g * 4 + j]);
#pragma unroll
          for (int j = 0; j < 4; ++j) acc[g * 4 + j] = MFMA16x32(af1, bf[g & 1][j][1], acc[g * 4 + j]);
        }
      }
      // K natural layout (tiles 0..3)
#pragma unroll
      for (int nt = 0; nt < 4; ++nt)
#pragma unroll
        for (int r = 0; r < 4; ++r)
          Kws[(size_t)(m0 + w * 16 + 4 * G + r) * 64 + nt * 16 + l15] = (_Float16)acc[nt][r];
      // V -> LDS bounce (frag-block layout emitted after the block barrier)
#pragma unroll
      for (int nt = 4; nt < 24; ++nt) {
        half4_t h = {(_Float16)acc[nt][0], (_Float16)acc[nt][1], (_Float16)acc[nt][2], (_Float16)acc[nt][3]};
        *(half4_t*)(Vb + ((nt - 4) * 16 + l15) * 72 + w * 16 + 4 * G) = h;
      }
    } else {
      // ---------------- Q over tokens m-tile --------------------------------
      const int wq = w - 4;
      const float qsc = 0.125f * 1.44269504088896f;  // 1/sqrt(64) * log2(e)
      const float* arow = tokens + (size_t)(m0 + wq * 16 + l15) * 320;
      float4_t ar[4];
      auto ldA = [&](int kc) {
        ar[0] = *(const float4_t*)(arow + kc * 64 + 8 * G);
        ar[1] = *(const float4_t*)(arow + kc * 64 + 8 * G + 4);
        ar[2] = *(const float4_t*)(arow + kc * 64 + 32 + 8 * G);
        ar[3] = *(const float4_t*)(arow + kc * 64 + 36 + 8 * G);
      };
      float4_t acc[4];
#pragma unroll
      for (int nt = 0; nt < 4; ++nt) acc[nt] = {0.f, 0.f, 0.f, 0.f};
      half8_t bq[2][4][2];
      auto ldWQ = [&](int buf, int kc) {
#pragma unroll
        for (int nt = 0; nt < 4; ++nt)
#pragma unroll
          for (int c = 0; c < 2; ++c)
            bq[buf][nt][c] = *(const half8_t*)(WQf + ((size_t)((kc * 4 + nt) * 2 + c) * 64 + lane) * 8);
      };
      ldA(0);
      ldWQ(0, 0);
      for (int kc = 0; kc < 5; ++kc) {
        half8_t af0 = {(_Float16)ar[0][0], (_Float16)ar[0][1], (_Float16)ar[0][2], (_Float16)ar[0][3],
                       (_Float16)ar[1][0], (_Float16)ar[1][1], (_Float16)ar[1][2], (_Float16)ar[1][3]};
        half8_t af1 = {(_Float16)ar[2][0], (_Float16)ar[2][1], (_Float16)ar[2][2], (_Float16)ar[2][3],
                       (_Float16)ar[3][0], (_Float16)ar[3][1], (_Float16)ar[3][2], (_Float16)ar[3][3]};
        if (kc < 4) { ldA(kc + 1); ldWQ((kc + 1) & 1, kc + 1); }
#pragma unroll
        for (int nt = 0; nt < 4; ++nt) acc[nt] = MFMA16x32(af0, bq[kc & 1][nt][0], acc[nt]);
#pragma unroll
        for (int nt = 0; nt < 4; ++nt) acc[nt] = MFMA16x32(af1, bq[kc & 1][nt][1], acc[nt]);
      }
#pragma unroll
      for (int nt = 0; nt < 4; ++nt)
#pragma unroll
        for (int r = 0; r < 4; ++r)
          Qws[(size_t)(m0 + wq * 16 + 4 * G + r) * 64 + nt * 16 + l15] = (_Float16)(acc[nt][r] * qsc);
    }
    __syncthreads();
    if (w < 4) {
      // V fragment-block stores: (b, s-chunk32, htile), lane L, j:
      // V[h=ht*16+(L&15)][s=ch*32+8*(L>>4)+j]
#pragma unroll
      for (int rep = 0; rep < 10; ++rep) {
        int idx = w * 10 + rep;
        int c2 = idx / 20, htl = idx % 20;
        half8_t fr = *(const half8_t*)(Vb + (htl * 16 + l15) * 72 + c2 * 32 + 8 * G);
        int sg = m0 + c2 * 32;
        int b = sg >> 12, c2b = (sg & 4095) >> 5;
        *(half8_t*)(Vws + ((size_t)((b * 128 + c2b) * 20 + htl)) * 512 + lane * 8) = fr;
      }
    }
  }
  gbar(512);

  // ======================= phase C: flash attention =========================
  // EXACT R0 flash structure (87.4us best; R1-R3 falsified all sync edits).
  // kbuf/pbuf aliased over the (now dead) Vb LDS.
  {
    _Float16* kb = smem;          // [2][2048] frag blocks (stile*2+c)*512+lane*8
    _Float16* pb = smem + 4096;   // [2][2048] frag blocks tt*512+lane*8
    const int b = (bx & 7) >> 1;                       // batch pinned per XCD pair
    const int tblk = ((bx & 1) * 32 + (bx >> 3)) * 64; // 64-query block
    const bool is_pv = (w < 4);
    const int sw = w - 4;
    const int stile = sw & 1, tthalf = sw >> 1;
    const int t2 = tid & 255;
    const int s_loc = t2 >> 3, e8 = t2 & 7;
    const int kdst = ((s_loc >> 4) * 2 + (e8 >> 2)) * 512 + ((e8 & 3) * 16 + (s_loc & 15)) * 8;
    const _Float16* kg = Kws + (size_t)(b * 4096) * 64 + s_loc * 64 + e8 * 8;
    const _Float16* vt_b = Vws + (size_t)b * 1310720;

    half8_t qf[2][2];
    float la[2] = {0.f, 0.f};
    float4_t oa[4][5];
#pragma unroll
    for (int tt = 0; tt < 4; ++tt)
#pragma unroll
      for (int ht = 0; ht < 5; ++ht) oa[tt][ht] = {0.f, 0.f, 0.f, 0.f};
    half8_t vcur[5], vnxt[5];

    // prologue: stage K(0), K(1); load Q frags
    if (!is_pv) {
      uint4 k0 = *(const uint4*)(kg);
      uint4 k1 = *(const uint4*)(kg + 2048);
      *(uint4*)(&kb[kdst]) = k0;
      *(uint4*)(&kb[2048 + kdst]) = k1;
#pragma unroll
      for (int tt2 = 0; tt2 < 2; ++tt2) {
        int tt = tthalf * 2 + tt2;
#pragma unroll
        for (int c = 0; c < 2; ++c)
          qf[tt2][c] = *(const half8_t*)(Qws + (size_t)(b * 4096 + tblk + tt * 16 + l15) * 64 + c * 32 + 8 * G);
      }
    }
    __syncthreads();

    // pre-step: S^T produces P(0); PV loads V(0)
    if (is_pv) {
#pragma unroll
      for (int ht = 0; ht < 5; ++ht)
        vcur[ht] = *(const half8_t*)(vt_b + (w * 5 + ht) * 512 + lane * 8);
    } else {
      half8_t af[2];
#pragma unroll
      for (int c = 0; c < 2; ++c)
        af[c] = *(const half8_t*)(&kb[(stile * 2 + c) * 512 + lane * 8]);
#pragma unroll
      for (int tt2 = 0; tt2 < 2; ++tt2) {
        float4_t sa = {0.f, 0.f, 0.f, 0.f};
#pragma unroll
        for (int c = 0; c < 2; ++c) sa = MFMA16x32(af[c], qf[tt2][c], sa);
        float e0 = exp2f(sa[0]), e1 = exp2f(sa[1]), e2 = exp2f(sa[2]), e3 = exp2f(sa[3]);
        la[tt2] += (e0 + e1) + (e2 + e3);
        int tt = tthalf * 2 + tt2;
        int Gp = stile * 2 + (G >> 1);
        half4_t p = {(_Float16)e0, (_Float16)e1, (_Float16)e2, (_Float16)e3};
        *(half4_t*)(&pb[tt * 512 + (Gp * 16 + l15) * 8 + 4 * (G & 1)]) = p;
      }
    }
    __syncthreads();

    // main loop: step i consumes P(i)/V(i), produces P(i+1), stages K(i+2)
    for (int i = 0; i < 128; ++i) {
      if (is_pv) {
        if (i < 127) {
#pragma unroll
          for (int ht = 0; ht < 5; ++ht)
            vnxt[ht] = *(const half8_t*)(vt_b + (size_t)(i + 1) * 10240 + (w * 5 + ht) * 512 + lane * 8);
        }
        half8_t pa[4];
#pragma unroll
        for (int tt = 0; tt < 4; ++tt)
          pa[tt] = *(const half8_t*)(&pb[(i & 1) * 2048 + tt * 512 + lane * 8]);
#pragma unroll
        for (int ht = 0; ht < 5; ++ht)
#pragma unroll
          for (int tt = 0; tt < 4; ++tt) oa[tt][ht] = MFMA16x32(pa[tt], vcur[ht], oa[tt][ht]);
#pragma unroll
        for (int ht = 0; ht < 5; ++ht) vcur[ht] = vnxt[ht];
      } else if (i < 127) {
        uint4 kreg;
        if (i < 126) kreg = *(const uint4*)(kg + (size_t)(i + 2) * 2048);
        half8_t af[2];
#pragma unroll
        for (int c = 0; c < 2; ++c)
          af[c] = *(const half8_t*)(&kb[((i + 1) & 1) * 2048 + (stile * 2 + c) * 512 + lane * 8]);
#pragma unroll
        for (int tt2 = 0; tt2 < 2; ++tt2) {
          float4_t sa = {0.f, 0.f, 0.f, 0.f};
#pragma unroll
          for (int c = 0; c < 2; ++c) sa = MFMA16x32(af[c], qf[tt2][c], sa);
          float e0 = exp2f(sa[0]), e1 = exp2f(sa[1]), e2 = exp2f(sa[2]), e3 = exp2f(sa[3]);
          la[tt2] += (e0 + e1) + (e2 + e3);
          int tt = tthalf * 2 + tt2;
          int Gp = stile * 2 + (G >> 1);
          half4_t p = {(_Float16)e0, (_Float16)e1, (_Float16)e2, (_Float16)e3};
          *(half4_t*)(&pb[((i + 1) & 1) * 2048 + tt * 512 + (Gp * 16 + l15) * 8 + 4 * (G & 1)]) = p;
        }
        if (i < 126) *(uint4*)(&kb[(i & 1) * 2048 + kdst]) = kreg;
      }
      __syncthreads();
    }

    // epilogue: l reduction (S^T waves), normalize + store (PV waves)
    if (!is_pv) {
#pragma unroll
      for (int tt2 = 0; tt2 < 2; ++tt2) {
        float v = la[tt2];
        v += __shfl_xor(v, 16);
        v += __shfl_xor(v, 32);
        if (lane < 16) larr[stile][tthalf * 2 + tt2][l15] = v;
      }
    }
    __syncthreads();
    if (tid < 64) linv[tid] = 1.0f / (larr[0][tid >> 4][tid & 15] + larr[1][tid >> 4][tid & 15]);
    __syncthreads();
    if (is_pv) {
#pragma unroll
      for (int tt = 0; tt < 4; ++tt)
#pragma unroll
        for (int r = 0; r < 4; ++r) {
          float inv = linv[tt * 16 + 4 * G + r];
          size_t row = (size_t)(b * 4096 + tblk + tt * 16 + 4 * G + r) * 320;
#pragma unroll
          for (int ht = 0; ht < 5; ++ht)
            out[row + w * 80 + ht * 16 + l15] = oa[tt][ht][r] * inv;
        }
    }
  }
}

// ---------------------------------------------------------------------------
extern "C" void kernel_launch(void* const* d_in, const int* in_sizes, int n_in,
                              void* d_out, int out_size, void* d_ws, size_t ws_size,
                              hipStream_t stream) {
  const float* tokens  = (const float*)d_in[0];  // [4,4096,320]
  const float* context = (const float*)d_in[1];  // [4,4096,768]
  const float* Wq      = (const float*)d_in[2];  // [64,320]
  const float* Wk      = (const float*)d_in[3];  // [64,768]
  const float* Wv      = (const float*)d_in[4];  // [320,768]

  _Float16* Qws = (_Float16*)d_ws;           // 2 MiB
  _Float16* Kws = Qws + (size_t)1048576;     // 2 MiB
  _Float16* Vws = Kws + (size_t)1048576;     // 10 MiB, fragment-block layout

  // Barrier counter + frag-layout W16 live in d_out scratch: both are done
  // being used before phase C's epilogue overwrites every byte of out.
  unsigned* syncp = (unsigned*)d_out;
  _Float16* W16  = (_Float16*)((char*)d_out + 256);

  hipMemsetAsync(d_out, 0, 8, stream);  // reset barrier counter each launch
  fused_kernel<<<dim3(256), dim3(512), 0, stream>>>(
      tokens, context, Wq, Wk, Wv, Qws, Kws, Vws, syncp, W16, (float*)d_out);
}

// Round 8
// 196.907 us; speedup vs baseline: 1.4299x; 1.4299x over previous
//
#include <hip/hip_runtime.h>
#include <hip/hip_bf16.h>

typedef _Float16 half4_t  __attribute__((ext_vector_type(4)));
typedef _Float16 half8_t  __attribute__((ext_vector_type(8)));
typedef float    float4_t __attribute__((ext_vector_type(4)));

#define MFMA16x32(a, b, c) __builtin_amdgcn_mfma_f32_16x16x32_f16(a, b, c, 0, 0, 0)

// ---------------------------------------------------------------------------
// Fused QKV projection -- EXACT R0 kernel (measured ~38.7us once harness
// fixed-overhead F~82us is accounted; both R4/R6 restructures were slower).
// grid.x = 1024: [0,512) V, [512,768) K, [768,1024) Q.
// ---------------------------------------------------------------------------
template <int KTOT, int NT, int MODE>
__device__ __forceinline__ void proj_body(const float* __restrict__ A,
                                          const float* __restrict__ W,
                                          _Float16* __restrict__ out, float sc,
                                          int m0, int n0, int htg0,
                                          _Float16* Ach, _Float16* Bch) {
  constexpr int NCH = KTOT / 64;
  constexpr int NTIL = NT / 16;
  const int tid = threadIdx.x, w = tid >> 6, lane = tid & 63;
  const int G = lane >> 4, l15 = lane & 15;

  float4_t acc[NTIL];
#pragma unroll
  for (int nt = 0; nt < NTIL; ++nt) acc[nt] = {0.f, 0.f, 0.f, 0.f};

  float4_t areg[4], wreg[NTIL];
  auto ldA = [&](int kc) {
#pragma unroll
    for (int t = 0; t < 4; ++t) {
      int idx = t * 256 + tid;
      areg[t] = *(const float4_t*)(A + (size_t)(m0 + (idx >> 4)) * KTOT + kc * 64 + (idx & 15) * 4);
    }
  };
  auto ldW = [&](int kc) {
#pragma unroll
    for (int t = 0; t < NTIL; ++t) {
      int idx = t * 256 + tid;
      wreg[t] = *(const float4_t*)(W + (size_t)(n0 + (idx >> 4)) * KTOT + kc * 64 + (idx & 15) * 4);
    }
  };

  ldA(0); ldW(0);
  for (int kc = 0; kc < NCH; ++kc) {
    __syncthreads();
#pragma unroll
    for (int t = 0; t < 4; ++t) {
      int idx = t * 256 + tid;
      half4_t h = {(_Float16)areg[t][0], (_Float16)areg[t][1], (_Float16)areg[t][2], (_Float16)areg[t][3]};
      *(half4_t*)(Ach + (idx >> 4) * 72 + (idx & 15) * 4) = h;
    }
#pragma unroll
    for (int t = 0; t < NTIL; ++t) {
      int idx = t * 256 + tid;
      half4_t h = {(_Float16)wreg[t][0], (_Float16)wreg[t][1], (_Float16)wreg[t][2], (_Float16)wreg[t][3]};
      *(half4_t*)(Bch + (idx >> 4) * 72 + (idx & 15) * 4) = h;
    }
    __syncthreads();
    if (kc + 1 < NCH) { ldA(kc + 1); ldW(kc + 1); }
#pragma unroll
    for (int c = 0; c < 2; ++c) {
      half8_t af = *(const half8_t*)(Ach + (w * 16 + l15) * 72 + c * 32 + 8 * G);
#pragma unroll
      for (int nt = 0; nt < NTIL; ++nt) {
        half8_t bf = *(const half8_t*)(Bch + (nt * 16 + l15) * 72 + c * 32 + 8 * G);
        acc[nt] = MFMA16x32(af, bf, acc[nt]);
      }
    }
  }

  if constexpr (MODE <= 1) {
#pragma unroll
    for (int nt = 0; nt < NTIL; ++nt)
#pragma unroll
      for (int r = 0; r < 4; ++r)
        out[(size_t)(m0 + w * 16 + 4 * G + r) * 64 + nt * 16 + l15] = (_Float16)(acc[nt][r] * sc);
  } else {
    __syncthreads();
#pragma unroll
    for (int nt = 0; nt < NTIL; ++nt) {
      half4_t h = {(_Float16)acc[nt][0], (_Float16)acc[nt][1], (_Float16)acc[nt][2], (_Float16)acc[nt][3]};
      *(half4_t*)(Bch + (nt * 16 + l15) * 72 + w * 16 + 4 * G) = h;
    }
    __syncthreads();
#pragma unroll
    for (int rep = 0; rep < 5; ++rep) {
      int idx = w * 5 + rep;
      int c2 = idx / 10, htl = idx % 10;
      half8_t fr = *(const half8_t*)(Bch + (htl * 16 + l15) * 72 + c2 * 32 + 8 * G);
      int sg = m0 + c2 * 32;
      int b = sg >> 12, c2b = (sg & 4095) >> 5;
      int htg = htg0 + htl;
      *(half8_t*)(out + ((size_t)((b * 128 + c2b) * 20 + htg)) * 512 + lane * 8) = fr;
    }
  }
}

__global__ __launch_bounds__(256, 2)
void qkv_proj_kernel(const float* __restrict__ tokens, const float* __restrict__ context,
                     const float* __restrict__ Wq, const float* __restrict__ Wk,
                     const float* __restrict__ Wv, _Float16* __restrict__ Q,
                     _Float16* __restrict__ K, _Float16* __restrict__ V) {
  __shared__ alignas(16) _Float16 smem[16128];  // Ach 64*72 + Bch 160*72
  _Float16* Ach = smem;
  _Float16* Bch = smem + 64 * 72;
  const int bx = blockIdx.x;
  const float qsc = 0.125f * 1.44269504088896f;  // 1/sqrt(64) * log2(e)
  if (bx < 512) {
    int y = bx >> 8, mb = bx & 255;
    proj_body<768, 160, 2>(context, Wv, V, 1.0f, mb * 64, y * 160, y * 10, Ach, Bch);
  } else if (bx < 768) {
    proj_body<768, 64, 1>(context, Wk, K, 1.0f, (bx - 512) * 64, 0, 0, Ach, Bch);
  } else {
    proj_body<320, 64, 0>(tokens, Wq, Q, qsc, (bx - 768) * 64, 0, 0, Ach, Bch);
  }
}

// ---------------------------------------------------------------------------
// Flash cross-attention, R0 producer/consumer structure with s-CHUNK = 64
// (R8 change). Rationale: R0 spends ~1640 cyc/iter vs 466 MFMA floor; the
// ~1170 overhead (barrier skew + S^T serial ds_read->MFMA->exp->ds_write
// chain) is per-ITERATION, so double the chunk -> 64 iters instead of 128,
// per-iter MFMA doubles (PV 40, S^T 8 per wave). Same shallow pipeline and
// one __syncthreads per chunk (R1-R3 falsified barrier-batching, staging
// remaps, raw-barrier variants on the 32-chunk version).
// Waves 0-3 (PV): h-slice 80; V global->reg, ping-pong via x2 unroll.
// Waves 4-7 (S^T): wave sw owns s-tile stile=sw (16 rows) x all 4 t-tiles.
// kbuf/pbuf[2][4096]: 8 frag-blocks of 512 halves per chunk. LDS ~33KB.
// No softmax max-subtraction (scores tiny); l-normalize in epilogue.
// ---------------------------------------------------------------------------
__global__ __launch_bounds__(512, 2)
void flash_kernel(const _Float16* __restrict__ Qg, const _Float16* __restrict__ Kg,
                  const _Float16* __restrict__ Vt, float* __restrict__ out) {
  __shared__ alignas(16) _Float16 kbuf[2][4096];  // blocks (stile*2+c)*512 + lane*8
  __shared__ alignas(16) _Float16 pbuf[2][4096];  // blocks (tt*2+sc)*512 + lane*8
  __shared__ float larr[4][4][16];
  __shared__ float linv[64];

  const int tid = threadIdx.x, w = tid >> 6, lane = tid & 63;
  const int G = lane >> 4, l15 = lane & 15;
  const int bx = blockIdx.x;
  const int b = (bx & 7) >> 1;                       // batch pinned per XCD pair
  const int tblk = ((bx & 1) * 32 + (bx >> 3)) * 64; // 64-query block

  const bool is_pv = (w < 4);
  const int sw = w - 4;                  // S^T wave index = its s-tile
  const int t2 = tid & 255;              // K-staging slot (S^T waves)
  const int s_loc = t2 >> 3, e8 = t2 & 7;            // s_loc 0..31 (+32 second store)
  const int kdst = ((s_loc >> 4) * 2 + (e8 >> 2)) * 512 + ((e8 & 3) * 16 + (s_loc & 15)) * 8;
  const _Float16* kg = Kg + (size_t)(b * 4096) * 64 + s_loc * 64 + e8 * 8;
  const _Float16* vt_b = Vt + (size_t)b * 1310720;

  half8_t qf[4][2];                      // S^T: Q frags for all 4 t-tiles
  float la[4] = {0.f, 0.f, 0.f, 0.f};
  float4_t oa[4][5];
#pragma unroll
  for (int tt = 0; tt < 4; ++tt)
#pragma unroll
    for (int ht = 0; ht < 5; ++ht) oa[tt][ht] = {0.f, 0.f, 0.f, 0.f};
  half8_t vb[2][2][5];                   // [unroll parity][sc][ht]

  // S^T step for 64-chunk j: wave sw computes S^T rows sw*16..+15 x t 0..63.
  // P(t,s): s = sw*16+4G+r, t = tt*16+l15 -> pbuf block tt*2+(sw>>1),
  // halfword ((l15 + 16*((sw&1)*2+(G>>1))))*8 + 4*(G&1) + r  (derived from
  // the 16x16x32 A-frag map; verified against the PV-read mapping).
  auto st_step = [&](int j) {
    half8_t af[2];
#pragma unroll
    for (int c = 0; c < 2; ++c)
      af[c] = *(const half8_t*)(&kbuf[j & 1][(sw * 2 + c) * 512 + lane * 8]);
    const int pbase = ((l15 + 16 * ((sw & 1) * 2 + (G >> 1)))) * 8 + 4 * (G & 1);
#pragma unroll
    for (int tt = 0; tt < 4; ++tt) {
      float4_t sa = {0.f, 0.f, 0.f, 0.f};
      sa = MFMA16x32(af[0], qf[tt][0], sa);
      sa = MFMA16x32(af[1], qf[tt][1], sa);
      float e0 = exp2f(sa[0]), e1 = exp2f(sa[1]), e2 = exp2f(sa[2]), e3 = exp2f(sa[3]);
      la[tt] += (e0 + e1) + (e2 + e3);
      half4_t p = {(_Float16)e0, (_Float16)e1, (_Float16)e2, (_Float16)e3};
      *(half4_t*)(&pbuf[j & 1][(tt * 2 + (sw >> 1)) * 512 + pbase]) = p;
    }
  };

  // ---- prologue: stage K(0), K(1) (8KB each, 2 stores/lane); load Q frags ----
  if (!is_pv) {
    uint4 k00 = *(const uint4*)(kg);
    uint4 k01 = *(const uint4*)(kg + 2048);
    uint4 k10 = *(const uint4*)(kg + 4096);
    uint4 k11 = *(const uint4*)(kg + 4096 + 2048);
    *(uint4*)(&kbuf[0][kdst]) = k00;
    *(uint4*)(&kbuf[0][kdst + 2048]) = k01;
    *(uint4*)(&kbuf[1][kdst]) = k10;
    *(uint4*)(&kbuf[1][kdst + 2048]) = k11;
#pragma unroll
    for (int tt = 0; tt < 4; ++tt)
#pragma unroll
      for (int c = 0; c < 2; ++c)
        qf[tt][c] = *(const half8_t*)(Qg + (size_t)(b * 4096 + tblk + tt * 16 + l15) * 64 + c * 32 + 8 * G);
  }
  __syncthreads();

  // ---- pre-step: S^T produces P(0); PV loads V(0) into vb[0] ----
  if (is_pv) {
#pragma unroll
    for (int sc = 0; sc < 2; ++sc)
#pragma unroll
      for (int ht = 0; ht < 5; ++ht)
        vb[0][sc][ht] = *(const half8_t*)(vt_b + (size_t)sc * 10240 + (w * 5 + ht) * 512 + lane * 8);
  } else {
    st_step(0);
  }
  __syncthreads();

  // ---- main loop: 64 chunks, x2 unroll for V ping-pong ----
  for (int ii = 0; ii < 64; ii += 2) {
#pragma unroll
    for (int u = 0; u < 2; ++u) {
      const int i = ii + u;
      if (is_pv) {
        if (i < 63) {
#pragma unroll
          for (int sc = 0; sc < 2; ++sc)
#pragma unroll
            for (int ht = 0; ht < 5; ++ht)
              vb[u ^ 1][sc][ht] = *(const half8_t*)(vt_b + (size_t)(2 * (i + 1) + sc) * 10240 + (w * 5 + ht) * 512 + lane * 8);
        }
        half8_t pa[4][2];
#pragma unroll
        for (int tt = 0; tt < 4; ++tt)
#pragma unroll
          for (int sc = 0; sc < 2; ++sc)
            pa[tt][sc] = *(const half8_t*)(&pbuf[i & 1][(tt * 2 + sc) * 512 + lane * 8]);
#pragma unroll
        for (int sc = 0; sc < 2; ++sc)
#pragma unroll
          for (int ht = 0; ht < 5; ++ht)
#pragma unroll
            for (int tt = 0; tt < 4; ++tt)
              oa[tt][ht] = MFMA16x32(pa[tt][sc], vb[u][sc][ht], oa[tt][ht]);
      } else {
        uint4 kr0, kr1;
        if (i < 62) {
          kr0 = *(const uint4*)(kg + (size_t)(i + 2) * 4096);
          kr1 = *(const uint4*)(kg + (size_t)(i + 2) * 4096 + 2048);
        }
        if (i < 63) st_step(i + 1);
        if (i < 62) {
          *(uint4*)(&kbuf[i & 1][kdst]) = kr0;
          *(uint4*)(&kbuf[i & 1][kdst + 2048]) = kr1;
        }
      }
      __syncthreads();
    }
  }

  // ---- epilogue: l reduction (S^T waves), normalize + store (PV waves) ----
  if (!is_pv) {
#pragma unroll
    for (int tt = 0; tt < 4; ++tt) {
      float v = la[tt];
      v += __shfl_xor(v, 16);
      v += __shfl_xor(v, 32);
      if (lane < 16) larr[sw][tt][l15] = v;
    }
  }
  __syncthreads();
  if (tid < 64)
    linv[tid] = 1.0f / (larr[0][tid >> 4][tid & 15] + larr[1][tid >> 4][tid & 15] +
                        larr[2][tid >> 4][tid & 15] + larr[3][tid >> 4][tid & 15]);
  __syncthreads();
  if (is_pv) {
#pragma unroll
    for (int tt = 0; tt < 4; ++tt)
#pragma unroll
      for (int r = 0; r < 4; ++r) {
        float inv = linv[tt * 16 + 4 * G + r];
        size_t row = (size_t)(b * 4096 + tblk + tt * 16 + 4 * G + r) * 320;
#pragma unroll
        for (int ht = 0; ht < 5; ++ht)
          out[row + w * 80 + ht * 16 + l15] = oa[tt][ht][r] * inv;
      }
  }
}

// ---------------------------------------------------------------------------
extern "C" void kernel_launch(void* const* d_in, const int* in_sizes, int n_in,
                              void* d_out, int out_size, void* d_ws, size_t ws_size,
                              hipStream_t stream) {
  const float* tokens  = (const float*)d_in[0];  // [4,4096,320]
  const float* context = (const float*)d_in[1];  // [4,4096,768]
  const float* Wq      = (const float*)d_in[2];  // [64,320]
  const float* Wk      = (const float*)d_in[3];  // [64,768]
  const float* Wv      = (const float*)d_in[4];  // [320,768]

  _Float16* Qws = (_Float16*)d_ws;           // 2 MiB
  _Float16* Kws = Qws + (size_t)1048576;     // 2 MiB
  _Float16* Vws = Kws + (size_t)1048576;     // 10 MiB, fragment-block layout

  qkv_proj_kernel<<<dim3(1024), 256, 0, stream>>>(tokens, context, Wq, Wk, Wv,
                                                  Qws, Kws, Vws);
  flash_kernel<<<dim3(256), 512, 0, stream>>>(Qws, Kws, Vws, (float*)d_out);
}